// Round 12
// baseline (156.056 us; speedup 1.0000x reference)
//
#include <hip/hip_runtime.h>
#include <stdint.h>
#include <math.h>

// Problem constants
#define NB_B 8
#define NB_S 512
#define NB_D 1024
#define NB_H 16
#define NB_HD 64
#define NP 196            // image patches: bidirectional prefix block
#define MTOT 4096         // B*S

// Workspace layout (offsets in bf16/short elements). Total 48 MB.
// ALL matrices that feed async16 staging (or wave-frag loads) are stored
// CHUNK-SWIZZLED: chunk (g = 16-row group, kb = 32-col block) = 512 shorts,
// [lane=quad*16+c][8 shorts], c = row%16, quad = (col%32)/8.
// => async16/frag reads are contiguous 1KB wave bursts (R9-verified win).
// WQ/WK/WV are contiguous & seamless in gn (global 16-col group 0..191),
// so qkv n-tiles may straddle weight boundaries (R12).
#define OFF_XB 0          // x bf16 swizzled:      [g 0..255][kb 0..31][64][8]
#define OFF_WQ 4194304    // w swizzled (each):    [gn 0..63][kb 0..31][64][8]
#define OFF_WK 5242880
#define OFF_WV 6291456
#define OFF_WO 7340032
#define OFF_Q  8388608    // Q swizzled: [bh][qg 0..31][dblk 0..1][64][8]
#define OFF_K  12582912   // K swizzled: [bh][kg 0..31][dblk 0..1][64][8]
#define OFF_VT 16777216   // V^T swizzled: [bh][dg 0..3][kblk 0..15][64][8]
#define OFF_CT 20971520   // ctx swizzled like XB: [g 0..255][kb 0..31][64][8]

typedef __attribute__((ext_vector_type(8))) short bf16x8;
typedef __attribute__((ext_vector_type(4))) float f32x4;
typedef __attribute__((ext_vector_type(4))) short s16x4;
typedef __attribute__((ext_vector_type(8))) short s16x8;

__device__ __forceinline__ short f2bf(float f) {
  union { float f; uint32_t u; } c; c.f = f;
  uint32_t r = (c.u + 0x7fffu + ((c.u >> 16) & 1u)) >> 16;   // RNE
  return (short)r;
}

// pack two fp32 -> one dword of two bf16 (round-half-up; softmax weights >=0)
__device__ __forceinline__ uint32_t pack2bf(float lo, float hi) {
  uint32_t ulo = __float_as_uint(lo) + 0x8000u;
  uint32_t uhi = __float_as_uint(hi) + 0x8000u;
  return __builtin_amdgcn_perm(uhi, ulo, 0x07060302u);  // [bf16(hi)|bf16(lo)]
}

__device__ __forceinline__ void async16(void* lds, const void* g) {
  // global -> LDS direct copy, 16B per lane; LDS dest = uniform base + lane*16
  __builtin_amdgcn_global_load_lds(
      (const __attribute__((address_space(1))) void*)g,
      (__attribute__((address_space(3))) void*)lds, 16, 0, 0);
}

// ---------------------------------------------------------------------------
// cvt5 v3: fp32 -> bf16 + chunk-swizzle via LDS transpose (R10-verified).
// ---------------------------------------------------------------------------
__global__ __launch_bounds__(256) void cvt5(const float* __restrict__ x,
                                            const float* __restrict__ wq,
                                            const float* __restrict__ wk,
                                            const float* __restrict__ wv,
                                            const float* __restrict__ wo,
                                            short* __restrict__ ws) {
  __shared__ uint32_t lt[16 * 513];   // 16 rows x 513 dwords (+pad: phase-2 conflict-free)
  int b = blockIdx.x, t = threadIdx.x;
  const float* src; short* dst; float scale;
  if (b < 256) {
    src = x + b * 16384;            // rows b*16 .. b*16+15
    dst = ws + OFF_XB + b * 16384;
    scale = 1.0f;
  } else {
    int wi = (b - 256) >> 6, gn = (b - 256) & 63;
    switch (wi) {
      case 0:  src = wq + gn * 16384; scale = 0.125f; break;
      case 1:  src = wk + gn * 16384; scale = 1.0f;   break;
      case 2:  src = wv + gn * 16384; scale = 1.0f;   break;
      default: src = wo + gn * 16384; scale = 1.0f;   break;
    }
    dst = ws + OFF_WQ + wi * 1048576 + gn * 16384;
  }
  // --- phase 1: coalesced float4 reads -> packed bf16 pairs in LDS ---
#pragma unroll
  for (int i = 0; i < 16; ++i) {
    int flat = t + i * 256;          // float4 id, 0..4095
    int row = flat >> 8, col4 = flat & 255;
    float4 v = *(const float4*)(src + flat * 4);
    uint32_t lo = (uint32_t)(uint16_t)f2bf(v.x * scale) |
                  ((uint32_t)(uint16_t)f2bf(v.y * scale) << 16);
    uint32_t hi = (uint32_t)(uint16_t)f2bf(v.z * scale) |
                  ((uint32_t)(uint16_t)f2bf(v.w * scale) << 16);
    lt[row * 513 + col4 * 2]     = lo;
    lt[row * 513 + col4 * 2 + 1] = hi;
  }
  __syncthreads();
  // --- phase 2: swizzled LDS gather -> contiguous 16B global writes ---
#pragma unroll
  for (int i = 0; i < 8; ++i) {
    int s = t + i * 256;             // chunk-slot id, 0..2047
    int kb = s >> 6, l = s & 63, quad = l >> 4, cc = l & 15;
    int base = cc * 513 + kb * 16 + quad * 4;
    union { uint32_t u[4]; s16x8 v; } o;
    o.u[0] = lt[base];     o.u[1] = lt[base + 1];
    o.u[2] = lt[base + 2]; o.u[3] = lt[base + 3];
    *(s16x8*)(dst + s * 8) = o.v;
  }
}

// ---------------------------------------------------------------------------
// QKV projection v6 (R12): 128m x 192n tiles over the CONCATENATED [Q|K|V]
// output (4096 x 3072) -> 32 x 16 = 512 blocks = exactly 2/CU, ONE
// co-residency round (R11's 768 blocks = 1.5 rounds left the tail ~1/3 of
// the dispatch half-idle). n-tiles straddle weight boundaries legally since
// WQ/WK/WV swizzled layouts concatenate seamlessly in gn.
// 4 waves, wave-tile 64m x 96n (acc 4x6). Per iter: 20 chunks (8 A + 12 B),
// 5 async16/wave, 28KB LDS, 24 wave-MFMA. Epilogue per 16-col group:
// wsel = nb16>>6 (uniform per (wn,j)); Q,K -> chunk-swizzled; V -> V_sw.
// ---------------------------------------------------------------------------
__global__ __launch_bounds__(256, 2) void gemm_qkv(short* __restrict__ ws) {
  __shared__ __align__(16) short As[8192];   // 8 chunks (128m x 32k)
  __shared__ __align__(16) short Bs[6144];   // 12 chunks (192n x 32k)
  int bx = blockIdx.x;              // 0..511
  int mt = bx >> 4, nt = bx & 15;
  int m0 = mt << 7;
  const short* A  = ws + OFF_XB;
  const short* Bw = ws + OFF_WQ;    // seamless gn addressing across Q,K,V
  int t = threadIdx.x, lane = t & 63, wvi = t >> 6;
  int c = lane & 15, quad = lane >> 4;
  int wm = wvi >> 1, wn = wvi & 1;  // wave tile 64m x 96n
  int g0 = mt << 3, gn0 = nt * 12;  // 16-row / 16-col group bases
  f32x4 acc[4][6] = {};

  for (int kk = 0; kk < 1024; kk += 32) {
    int kb = kk >> 5;
#pragma unroll
    for (int i = 0; i < 5; ++i) {
      int ch = wvi * 5 + i;         // 0..19 (wave 3 stages 4: ch 15..18, +19 below)
      if (ch < 8) {
        async16(&As[ch << 9], A + ((g0 + ch) * 32 + kb) * 512 + lane * 8);
      } else {
        int cb = ch - 8;
        async16(&Bs[cb << 9], Bw + ((gn0 + cb) * 32 + kb) * 512 + lane * 8);
      }
    }
    if (wvi == 3)                   // 20th chunk (uniform branch per wave)
      async16(&Bs[11 << 9], Bw + ((gn0 + 11) * 32 + kb) * 512 + lane * 8);
    __syncthreads();                // drains vmcnt for global_load_lds

    bf16x8 af[4], bfr[6];
#pragma unroll
    for (int i = 0; i < 4; ++i) af[i]  = *(const bf16x8*)&As[((wm * 4 + i) << 9) + lane * 8];
#pragma unroll
    for (int j = 0; j < 6; ++j) bfr[j] = *(const bf16x8*)&Bs[((wn * 6 + j) << 9) + lane * 8];
#pragma unroll
    for (int i = 0; i < 4; ++i)
#pragma unroll
      for (int j = 0; j < 6; ++j)
        acc[i][j] = __builtin_amdgcn_mfma_f32_16x16x32_bf16(af[i], bfr[j], acc[i][j], 0, 0, 0);
    __syncthreads();                // protect LDS before next stage
  }

#pragma unroll
  for (int i = 0; i < 4; ++i) {
#pragma unroll
    for (int j = 0; j < 6; ++j) {
      int nb16 = gn0 + wn * 6 + j;  // global 16-col group, 0..191
      int wsel = nb16 >> 6;         // 0=Q 1=K 2=V (uniform per (wn,j))
      int n = ((nb16 & 63) << 4) + c;   // feature within the selected matrix
      int h = n >> 6, d = n & 63;
      int mq = m0 + wm * 64 + i * 16 + quad * 4; // first of the 4 rows (reg dim)
      int bb = mq >> 9, srow = mq & 511;
      if (wsel < 2) {
        // Q_sw / K_sw: [bh][g][dblk][lane=qk*16+(row%16)][jd]; row%16=quad*4+r
        int dblk = d >> 5, qk = (d >> 3) & 3, jd = d & 7;
        int g = srow >> 4;
        short* outp = ws + (wsel == 0 ? OFF_Q : OFF_K);
        size_t base = (size_t)(bb * 16 + h) * 32768 +
                      (size_t)(((g * 2 + dblk) * 64 + qk * 16 + quad * 4)) * 8 + jd;
#pragma unroll
        for (int r = 0; r < 4; ++r) outp[base + r * 8] = f2bf(acc[i][j][r]);
      } else {
        // V_sw: [bh][dg][kblk][lane=qv*16+(d%16)][jv]; keys srow..srow+3
        int dg = d >> 4, cv = d & 15;
        int kblk = srow >> 5, qv = (srow >> 3) & 3, jv = srow & 7;
        s16x4 o;
#pragma unroll
        for (int r = 0; r < 4; ++r) o[r] = f2bf(acc[i][j][r]);
        *(s16x4*)&ws[OFF_VT + (size_t)(bb * 16 + h) * 32768 +
                     (size_t)((dg * 16 + kblk) * 64 + qv * 16 + cv) * 8 + jv] = o;
      }
    }
  }
}

// ---------------------------------------------------------------------------
// Attention v6 (R11, unchanged): 128-key chunks, swizzled 1KB-burst staging.
// ---------------------------------------------------------------------------
__global__ __launch_bounds__(256, 2) void attn(short* __restrict__ ws) {
  __shared__ __align__(16) short Kb[8192];   // 16 chunks: [kgrel 0..7][dblk 0..1]
  __shared__ __align__(16) short Vb[8192];   // 16 chunks: [dg 0..3][kbrel 0..3]
  int bi = blockIdx.x;              // 0..511
  int bh = bi >> 2, qcr = bi & 3;
  int qc = (qcr + bh + 2 * (bh >> 6)) & 3;   // rotate so CU pairs mix light/heavy
  int t = threadIdx.x, lane = t & 63, wvi = t >> 6;
  int c = lane & 15, quad = lane >> 4;
  const short* Qsw  = ws + OFF_Q  + (size_t)bh * 32768;
  const short* Ksw  = ws + OFF_K  + (size_t)bh * 32768;
  const short* Vsw  = ws + OFF_VT + (size_t)bh * 32768;
  short* ct = ws + OFF_CT;
  int b = bh >> 4, h = bh & 15;

  int qt0 = qc * 128 + wvi * 32;    // two 16-row subtiles per wave
  int qt1 = qt0 + 16;
  int kn0 = (qt0 + 16 > NP) ? (qt0 + 16) : NP;
  int kn1 = (qt1 + 16 > NP) ? (qt1 + 16) : NP;
  int knb = (qc * 128 + 128 > NP) ? (qc * 128 + 128) : NP;
  int NCH = (knb + 127) >> 7;       // 128-key chunks staged by the block

  // Q^T B-frags from Q_sw (contiguous 1KB wave bursts)
  int qg0 = qt0 >> 4, qg1 = qt1 >> 4;
  bf16x8 q00 = *(const bf16x8*)(Qsw + ((qg0 * 2 + 0) * 64 + lane) * 8);
  bf16x8 q01 = *(const bf16x8*)(Qsw + ((qg0 * 2 + 1) * 64 + lane) * 8);
  bf16x8 q10 = *(const bf16x8*)(Qsw + ((qg1 * 2 + 0) * 64 + lane) * 8);
  bf16x8 q11 = *(const bf16x8*)(Qsw + ((qg1 * 2 + 1) * 64 + lane) * 8);

  f32x4 acc0[4] = {}, acc1[4] = {}; // ctx^T accumulators per subtile
  float l0 = 0.0f, l1 = 0.0f;       // in-lane softmax denominators
  int L0 = c + ((quad & 1) << 5);   // transpose source lane
  bool hilo = quad >= 2;

  for (int chn = 0; chn < NCH; ++chn) {
    int k0 = chn << 7;              // chunk covers keys k0 .. k0+127
    // --- stage 16 K-chunks + 16 V-chunks, 8 async16 per wave ---
    {
      int kg0 = k0 >> 4;            // first 16-key group
      int kblk0 = k0 >> 5;          // first 32-key block
#pragma unroll
      for (int i = 0; i < 4; ++i) {
        int ch = wvi * 4 + i;       // 0..15, wave-uniform
        int kgrel = ch >> 1, f = ch & 1;
        async16(&Kb[ch << 9], Ksw + (((kg0 + kgrel) * 2 + f) * 64 + lane) * 8);
        int dg = ch >> 2, kbrel = ch & 3;
        async16(&Vb[ch << 9], Vsw + ((dg * 16 + kblk0 + kbrel) * 64 + lane) * 8);
      }
    }
    __syncthreads();                // drains vmcnt for global_load_lds

#pragma unroll
    for (int hf = 0; hf < 2; ++hf) {
      int kh = k0 + (hf << 6);      // this 64-key half
      // K A-frags [m=key16][k=d] and V^T A-frags [m=d16][k=key32+..]
      bf16x8 ak[4][2], av[4][2];
#pragma unroll
      for (int mb = 0; mb < 4; ++mb)
#pragma unroll
        for (int f = 0; f < 2; ++f) {
          ak[mb][f] = *(const bf16x8*)&Kb[((((hf * 4 + mb) << 1) + f) << 9) + lane * 8];
          av[mb][f] = *(const bf16x8*)&Vb[(((mb << 2) + (hf << 1) + f) << 9) + lane * 8];
        }

#pragma unroll
      for (int s = 0; s < 2; ++s) {
        int qt = s ? qt1 : qt0;
        int kn = s ? kn1 : kn0;
        if (kh >= kn) continue;     // subtile finished for this half
        bf16x8 bq0 = s ? q10 : q00;
        bf16x8 bq1 = s ? q11 : q01;
        f32x4* acc = s ? acc1 : acc0;

        // --- S^T = K . Q^T : 4 m-blocks of 16 keys ---
        float p[4][4];
#pragma unroll
        for (int mb = 0; mb < 4; ++mb) {
          f32x4 st = {};
          st = __builtin_amdgcn_mfma_f32_16x16x32_bf16(ak[mb][0], bq0, st, 0, 0, 0);
          st = __builtin_amdgcn_mfma_f32_16x16x32_bf16(ak[mb][1], bq1, st, 0, 0, 0);
#pragma unroll
          for (int r = 0; r < 4; ++r) p[mb][r] = __expf(st[r]);
        }

        // --- prefix/causal mask (only halves that can contain invalid keys) ---
        if ((kh + 64 > NP) && (kh + 64 > qt + 1)) {
          int row = qt + c;
#pragma unroll
          for (int mb = 0; mb < 4; ++mb)
#pragma unroll
            for (int r = 0; r < 4; ++r) {
              int key = kh + mb * 16 + (quad << 2) + r;
              bool v = (row < NP) ? (key < NP) : (key <= row);
              p[mb][r] = v ? p[mb][r] : 0.0f;
            }
        }
        float ls = 0.0f;
#pragma unroll
        for (int mb = 0; mb < 4; ++mb)
#pragma unroll
          for (int r = 0; r < 4; ++r) ls += p[mb][r];
        if (s) l1 += ls; else l0 += ls;

        // --- per 32-key half: transpose to B-frag (R3-verified), then PV ---
#pragma unroll
        for (int hh = 0; hh < 2; ++hh) {
          float* pa = p[2 * hh];    // keys kh+32hh+{4quad'+r}
          float* pb = p[2 * hh + 1];
          uint32_t e0 = pack2bf(pa[0], pa[1]);
          uint32_t e1 = pack2bf(pa[2], pa[3]);
          uint32_t e2 = pack2bf(pb[0], pb[1]);
          uint32_t e3 = pack2bf(pb[2], pb[3]);
          uint32_t a0 = (uint32_t)__shfl((int)e0, L0);
          uint32_t b0 = (uint32_t)__shfl((int)e1, L0);
          uint32_t a1 = (uint32_t)__shfl((int)e0, L0 + 16);
          uint32_t b1 = (uint32_t)__shfl((int)e1, L0 + 16);
          uint32_t c0 = (uint32_t)__shfl((int)e2, L0);
          uint32_t d0 = (uint32_t)__shfl((int)e3, L0);
          uint32_t c1 = (uint32_t)__shfl((int)e2, L0 + 16);
          uint32_t d1 = (uint32_t)__shfl((int)e3, L0 + 16);
          union { uint32_t u[4]; bf16x8 v; } bp;
          bp.u[0] = hilo ? c0 : a0;
          bp.u[1] = hilo ? d0 : b0;
          bp.u[2] = hilo ? c1 : a1;
          bp.u[3] = hilo ? d1 : b1;
#pragma unroll
          for (int db = 0; db < 4; ++db)
            acc[db] = __builtin_amdgcn_mfma_f32_16x16x32_bf16(av[db][hh], bp.v, acc[db], 0, 0, 0);
        }
      }
    }
    __syncthreads();                // protect LDS before next stage
  }

  // --- finalize: quad-reduce l, normalize, store ctx SWIZZLED (CT_sw) ---
#pragma unroll
  for (int s = 0; s < 2; ++s) {
    float l = s ? l1 : l0;
    f32x4* acc = s ? acc1 : acc0;
    int qt = s ? qt1 : qt0;
    l += __shfl_xor(l, 16);
    l += __shfl_xor(l, 32);
    float inv = 1.0f / l;
    int g = (b * 512 + qt) >> 4;    // 16-row group (qt multiple of 16)
#pragma unroll
    for (int db = 0; db < 4; ++db) {
      int col0 = h * 64 + db * 16 + quad * 4;   // first of 4 cols (r-run)
      int kb = col0 >> 5, qp = (col0 & 31) >> 3, jo = col0 & 7;
      s16x4 o;
#pragma unroll
      for (int r = 0; r < 4; ++r) o[r] = f2bf(acc[db][r] * inv);
      *(s16x4*)&ct[(size_t)((g * 32 + kb) * 64 + qp * 16 + c) * 8 + jo] = o;
    }
  }
}

// ---------------------------------------------------------------------------
// Output projection (R9 structure, unchanged): 64m x 128n, BK=64, 512 blocks,
// swizzled 1KB-burst staging from CT_sw / WO_sw.
// ---------------------------------------------------------------------------
__global__ __launch_bounds__(256, 2) void gemm_out(const short* __restrict__ ws,
                                                   const float* __restrict__ bias,
                                                   float* __restrict__ out) {
  __shared__ __align__(16) short As[4096];   // 8 chunks
  __shared__ __align__(16) short Bs[8192];   // 16 chunks
  int bx = blockIdx.x;              // 0..511
  int mt = bx >> 3, nt = bx & 7;
  int m0 = mt << 6, n0 = nt << 7;
  const short* A  = ws + OFF_CT;
  const short* Bw = ws + OFF_WO;
  int t = threadIdx.x, lane = t & 63, wvi = t >> 6;
  int c = lane & 15, quad = lane >> 4;
  int wm = wvi >> 1, wn = wvi & 1;   // wave tile 32m x 64n
  int g0 = m0 >> 4, gn0 = n0 >> 4;
  f32x4 acc[2][4] = {};

  for (int kk = 0; kk < 1024; kk += 64) {
    int kb = kk >> 5;
#pragma unroll
    for (int i = 0; i < 6; ++i) {
      int ch = wvi * 6 + i;
      if (ch < 8) {
        int mg = ch >> 1, kh = ch & 1;
        async16(&As[ch << 9], A + ((g0 + mg) * 32 + kb + kh) * 512 + lane * 8);
      } else {
        int cb = ch - 8, mg = cb >> 1, kh = cb & 1;
        async16(&Bs[cb << 9], Bw + ((gn0 + mg) * 32 + kb + kh) * 512 + lane * 8);
      }
    }
    __syncthreads();                // drains vmcnt for global_load_lds

    bf16x8 af[2][2], bfr[4][2];
#pragma unroll
    for (int i = 0; i < 2; ++i)
#pragma unroll
      for (int kh = 0; kh < 2; ++kh)
        af[i][kh] = *(const bf16x8*)&As[((((wm * 2 + i) << 1) + kh) << 9) + lane * 8];
#pragma unroll
    for (int j = 0; j < 4; ++j)
#pragma unroll
      for (int kh = 0; kh < 2; ++kh)
        bfr[j][kh] = *(const bf16x8*)&Bs[((((wn * 4 + j) << 1) + kh) << 9) + lane * 8];
#pragma unroll
    for (int kh = 0; kh < 2; ++kh)
#pragma unroll
      for (int i = 0; i < 2; ++i)
#pragma unroll
        for (int j = 0; j < 4; ++j)
          acc[i][j] = __builtin_amdgcn_mfma_f32_16x16x32_bf16(af[i][kh], bfr[j][kh], acc[i][j], 0, 0, 0);
    __syncthreads();                // protect LDS before next stage
  }

#pragma unroll
  for (int j = 0; j < 4; ++j) {
    int n = n0 + wn * 64 + j * 16 + c;
    float bj = bias[n];
#pragma unroll
    for (int i = 0; i < 2; ++i) {
      int mq = m0 + wm * 32 + i * 16 + quad * 4;
#pragma unroll
      for (int r = 0; r < 4; ++r)
        out[(size_t)(mq + r) * 1024 + n] = acc[i][j][r] + bj;
    }
  }
}

extern "C" void kernel_launch(void* const* d_in, const int* in_sizes, int n_in,
                              void* d_out, int out_size, void* d_ws, size_t ws_size,
                              hipStream_t stream) {
  (void)in_sizes; (void)n_in; (void)out_size; (void)ws_size;  // needs 48 MB of d_ws
  const float* x  = (const float*)d_in[0];
  const float* wq = (const float*)d_in[1];
  const float* wk = (const float*)d_in[2];
  const float* wv = (const float*)d_in[3];
  const float* wo = (const float*)d_in[4];
  const float* bo = (const float*)d_in[5];
  short* ws = (short*)d_ws;
  float* out = (float*)d_out;

  cvt5<<<512, 256, 0, stream>>>(x, wq, wk, wv, wo, ws);
  gemm_qkv<<<512, 256, 0, stream>>>(ws);
  attn<<<512, 256, 0, stream>>>(ws);
  gemm_out<<<512, 256, 0, stream>>>(ws, bo, out);
}